// Round 7
// baseline (2096.439 us; speedup 1.0000x reference)
//
#include <hip/hip_runtime.h>
#include <math.h>

#define TT 512
#define DPOI 256
#define DIN 260
#define DHID 356
#define DOUTD 512
#define G3 1536

// Blocks 0..GB-1: GRU workers (R6 protocol: 4B {bf16|tag16} payloads, 2-deep
// staggered pipelined polling, race-fixed). Blocks GB..GB+PREB-1: producer
// blocks, each computing the full pre-pipeline (features+LN+MLP1+MLP2+gi) for
// 2 timesteps and publishing per-t ready tags. Workers gate their gi prefetch
// (off the critical path) on ready[s+1]. 264 blocks x 1024 thr = guaranteed
// co-resident (capacity 512 slots) regardless of dispatch order.
#define GB 8
#define HU (DOUTD / GB)      // 64 hidden units per block
#define NRR (3 * HU)         // 192 w_hh rows per block
#define NPAY DOUTD           // 512 dword payload units per step
#define PREB 256             // producer blocks (2 timesteps each)
#define NZ4 ((TT * NPAY + TT) / 4)   // uint4s to zero: hcomm + ready

// ---------------- init: zero hcomm tags + ready flags (every graph iteration) ----------------
__global__ void init_kernel(uint4* __restrict__ p) {
    int i = blockIdx.x * blockDim.x + threadIdx.x;
    int stride = gridDim.x * blockDim.x;
    uint4 z; z.x = 0u; z.y = 0u; z.z = 0u; z.w = 0u;
    for (; i < NZ4; i += stride) p[i] = z;
}

// ---------------- mega kernel: workers + producers ----------------
__global__ __launch_bounds__(1024)
void mega_kernel(const int* __restrict__ idx, const float* __restrict__ timef,
                 const float* __restrict__ latlon, const float* __restrict__ emb,
                 const float* __restrict__ lnw, const float* __restrict__ lnb,
                 const float* __restrict__ w1, const float* __restrict__ b1,
                 const float* __restrict__ w2, const float* __restrict__ b2,
                 const float* __restrict__ wih, const float* __restrict__ bih,
                 const float* __restrict__ whh, const float* __restrict__ bhh,
                 float* __restrict__ gi, float* __restrict__ hs,
                 unsigned* __restrict__ hcomm, unsigned* __restrict__ ready) {
    int tid = threadIdx.x;     // 0..1023
    int wave = tid >> 6, lane = tid & 63;

    if (blockIdx.x >= GB) {
        // ================= producer path: pre for t = 2*pb, 2*pb+1 =================
        __shared__ float xl[DIN];
        __shared__ float h1l[DHID];
        __shared__ alignas(16) float x2l[DPOI];
        __shared__ float red[16];
        __shared__ float mu_s, rs_s;
        int pb = blockIdx.x - GB;

        for (int half = 0; half < 2; ++half) {
            int t = pb * 2 + half;

            // --- features (lanes 0..3 of wave 0 only) ---
            float fv = 0.f;
            if (tid < 4) {
                float tv = fminf(fmaxf(timef[t], 0.f), 1.f);
                const float TWO_PI = 6.28318530717958647692f;
                float f0 = sinf(TWO_PI * tv);
                float f1 = cosf(TWO_PI * tv);
                float f2 = 0.f, f3 = 0.f;
                if (t > 0) {
                    float tp = fminf(fmaxf(timef[t - 1], 0.f), 1.f);
                    float d = tv - tp;
                    d = d - floorf(d);          // jnp.mod(x, 1.0)
                    f2 = log1pf(d * 24.f);
                    int i0 = idx[t - 1], i1 = idx[t];
                    float la0 = latlon[2 * (size_t)i0], lo0 = latlon[2 * (size_t)i0 + 1];
                    float la1 = latlon[2 * (size_t)i1], lo1 = latlon[2 * (size_t)i1 + 1];
                    const float D2R = 0.01745329251994329577f;
                    float lat1 = fminf(fmaxf(la0, -90.f), 90.f) * D2R;
                    float lon1 = fminf(fmaxf(lo0, -180.f), 180.f) * D2R;
                    float lat2 = fminf(fmaxf(la1, -90.f), 90.f) * D2R;
                    float lon2 = fminf(fmaxf(lo1, -180.f), 180.f) * D2R;
                    float dlat = (lat2 - lat1) * 0.5f, dlon = (lon2 - lon1) * 0.5f;
                    float sdlat = sinf(dlat), sdlon = sinf(dlon);
                    float a = sdlat * sdlat +
                              fminf(fmaxf(cosf(lat1), -1.f), 1.f) * fminf(fmaxf(cosf(lat2), -1.f), 1.f) * sdlon * sdlon;
                    float aa = fminf(fmaxf(a, 0.f), 1.f);
                    float bb = fminf(fmaxf(1.f - a, 1e-12f), 1.f);
                    float cc = 2.f * atan2f(sqrtf(aa), sqrtf(bb));
                    f3 = log1pf(6371.0088f * cc);
                }
                fv = (tid == 0) ? f0 : (tid == 1) ? f1 : (tid == 2) ? f2 : f3;
            }

            float v0 = (tid < 256) ? emb[(size_t)idx[t] * DPOI + tid] : 0.f;
            float v1 = (tid < 4) ? fv : 0.f;

            // --- layernorm over 260 elements (16-wave reduce) ---
            float s = v0 + v1;
            for (int o = 32; o; o >>= 1) s += __shfl_down(s, o, 64);
            if (lane == 0) red[wave] = s;
            __syncthreads();
            if (tid == 0) {
                float mm = 0.f;
                for (int i = 0; i < 16; ++i) mm += red[i];
                mu_s = mm * (1.f / 260.f);
            }
            __syncthreads();
            float mu = mu_s;
            float d0 = (tid < 256) ? (v0 - mu) : 0.f;
            float d1 = (tid < 4) ? (v1 - mu) : 0.f;
            float sq = d0 * d0 + d1 * d1;
            for (int o = 32; o; o >>= 1) sq += __shfl_down(sq, o, 64);
            __syncthreads();            // protect red[] reads above
            if (lane == 0) red[wave] = sq;
            __syncthreads();
            if (tid == 0) {
                float vv = 0.f;
                for (int i = 0; i < 16; ++i) vv += red[i];
                rs_s = rsqrtf(vv * (1.f / 260.f) + 1e-5f);
            }
            __syncthreads();
            float rs = rs_s;
            if (tid < 256) xl[tid] = d0 * rs * lnw[tid] + lnb[tid];
            if (tid < 4)   xl[256 + tid] = d1 * rs * lnw[256 + tid] + lnb[256 + tid];
            __syncthreads();

            // --- mlp1: x @ w1 + b1, gelu -> h1 (LDS) ---
            if (tid < DHID) {
                float acc = b1[tid];
                #pragma unroll 4
                for (int k = 0; k < DIN; ++k) acc = fmaf(xl[k], w1[k * DHID + tid], acc);
                h1l[tid] = 0.5f * acc * (1.f + erff(acc * 0.70710678118654752440f));
            }
            __syncthreads();

            // --- mlp2: h1 @ w2 + b2 -> x2 (LDS) ---
            if (tid < DPOI) {
                float acc = b2[tid];
                #pragma unroll 4
                for (int k = 0; k < DHID; ++k) acc = fmaf(h1l[k], w2[k * DPOI + tid], acc);
                x2l[tid] = acc;
            }
            __syncthreads();

            // --- gi: x2 @ w_ih.T + b_ih (1536 rows over 16 waves) ---
            // agent-scope write-through stores: same-kernel consumers (workers)
            // bypass L1/L2 on their side, so the data must be at the coherence
            // point — kernel-boundary visibility does not apply here.
            float4 xv = ((const float4*)x2l)[lane];
            for (int r = wave; r < G3; r += 16) {
                float4 wv = ((const float4*)(wih + (size_t)r * DPOI))[lane];
                float sd = xv.x * wv.x + xv.y * wv.y + xv.z * wv.z + xv.w * wv.w;
                for (int o = 32; o; o >>= 1) sd += __shfl_down(sd, o, 64);
                if (lane == 0)
                    __hip_atomic_store(&gi[(size_t)t * G3 + r], sd + bih[r],
                                       __ATOMIC_RELAXED, __HIP_MEMORY_SCOPE_AGENT);
            }
            __syncthreads();   // per-wave vmcnt(0) drain before barrier -> gi visible
            if (tid == 0)
                __hip_atomic_store(&ready[t], 1u, __ATOMIC_RELAXED,
                                   __HIP_MEMORY_SCOPE_AGENT);
            __syncthreads();   // protect LDS reuse across halves
        }
        return;
    }

    // ================= worker path (R6 protocol, heaters removed) =================
    __shared__ alignas(16) float hprev[DOUTD];   // 2 KB
    __shared__ float gsum[NRR];                  // 768 B

    int b = blockIdx.x;        // 0..7
    int jbase = b * HU;
    int g4 = lane >> 4, l4 = lane & 15;
    int rr0 = wave * 12 + g4 * 3;      // this lane-group's 3 rows

    // --- W_hh fragments -> f32 registers. Lane covers k = m*64 + l4*4 + {0..3} ---
    float4 wf0[8], wf1[8], wf2[8];
    float bl0, bl1, bl2;
    {
        int r0 = rr0, r1 = rr0 + 1, r2 = rr0 + 2;
        const float4* p0 = (const float4*)(whh + (size_t)((r0 >> 6) * DOUTD + jbase + (r0 & 63)) * DOUTD);
        const float4* p1 = (const float4*)(whh + (size_t)((r1 >> 6) * DOUTD + jbase + (r1 & 63)) * DOUTD);
        const float4* p2 = (const float4*)(whh + (size_t)((r2 >> 6) * DOUTD + jbase + (r2 & 63)) * DOUTD);
        #pragma unroll
        for (int m = 0; m < 8; ++m) {
            wf0[m] = p0[m * 16 + l4];
            wf1[m] = p1[m * 16 + l4];
            wf2[m] = p2[m * 16 + l4];
        }
        bl0 = bhh[(r0 >> 6) * DOUTD + jbase + (r0 & 63)];
        bl1 = bhh[(r1 >> 6) * DOUTD + jbase + (r1 & 63)];
        bl2 = bhh[(r2 >> 6) * DOUTD + jbase + (r2 & 63)];
    }
    if (tid < DOUTD) hprev[tid] = 0.f;
    __syncthreads();

    const float4* hp4 = (const float4*)hprev;
    long budget = 3000;        // poll-loop re-entry budget (deadlock -> numeric fail)
    long rbudget = 1000000;    // gi-ready spin budget (covers producer startup)

    // gi prefetch (gate wave), gated on ready[0]; agent-scope loads (same-kernel
    // producer; normal loads could hit stale per-XCD L2 lines from a previous
    // graph iteration).
    float gir = 0.f, giz = 0.f, gin = 0.f, hreg = 0.f;
    if (tid < HU) {
        while (__hip_atomic_load(&ready[0], __ATOMIC_RELAXED,
                                 __HIP_MEMORY_SCOPE_AGENT) == 0u) {
            if (--rbudget < 0) break;
        }
        int j = jbase + tid;
        gir = __hip_atomic_load(&gi[j], __ATOMIC_RELAXED, __HIP_MEMORY_SCOPE_AGENT);
        giz = __hip_atomic_load(&gi[DOUTD + j], __ATOMIC_RELAXED, __HIP_MEMORY_SCOPE_AGENT);
        gin = __hip_atomic_load(&gi[2 * DOUTD + j], __ATOMIC_RELAXED, __HIP_MEMORY_SCOPE_AGENT);
    }

    for (int s = 0; s < TT; ++s) {
        unsigned pa = 0, pb2 = 0;
        if (s > 0) {
            // waves 4..11 poll: wave (4+wsrc) covers producer block wsrc's 64
            // units; the wave matching our own block skips (self-published).
            if (wave >= 4 && wave < 12 && (wave - 4) != b) {
                int u = ((wave - 4) << 6) + lane;
                const unsigned* ap = hcomm + (size_t)(s - 1) * NPAY + u;
                unsigned tag = (unsigned)s & 0xffffu;   // producer stored ((s-1)+1)
                // prime slot A
                asm volatile("global_load_dword %0, %1, off sc0 sc1"
                             : "=v"(pa) : "v"(ap) : "memory");
                // stagger ~RT/2: dependent FMA chain
                float xx = (float)(lane + 1) * 1e-6f;
                #pragma unroll
                for (int q = 0; q < 256; ++q) xx = fmaf(xx, 1.0000002f, 1.1920929e-7f);
                // prime slot B (chain feeds in as dummy input -> ordered after spin)
                asm volatile("global_load_dword %0, %1, off sc0 sc1"
                             : "=v"(pb2) : "v"(ap), "v"(xx) : "memory");
                // 2-deep round-robin pipelined poll; tag-gated; bounded.
                do {
                    unsigned tmp; int scnt;
                    asm volatile(
                        "s_movk_i32 %[cnt], 64\n\t"
                        "1:\n\t"
                        "s_waitcnt vmcnt(1)\n\t"
                        "v_and_b32 %[t], 0xffff, %[pa]\n\t"
                        "v_cmp_ne_u32 vcc, %[tag], %[t]\n\t"
                        "s_cbranch_vccz 9f\n\t"
                        "global_load_dword %[pa], %[ptr], off sc0 sc1\n\t"
                        "s_waitcnt vmcnt(1)\n\t"
                        "v_and_b32 %[t], 0xffff, %[pb]\n\t"
                        "v_cmp_ne_u32 vcc, %[tag], %[t]\n\t"
                        "s_cbranch_vccz 8f\n\t"
                        "global_load_dword %[pb], %[ptr], off sc0 sc1\n\t"
                        "s_sub_u32 %[cnt], %[cnt], 1\n\t"
                        "s_cmp_lg_u32 %[cnt], 0\n\t"
                        "s_cbranch_scc1 1b\n\t"
                        "s_branch 9f\n\t"
                        "8:\n\t"
                        "s_waitcnt vmcnt(0)\n\t"          // drain pa's in-flight reload
                        "v_mov_b32 %[pa], %[pb]\n\t"
                        "9:\n\t"
                        : [pa]"+v"(pa), [pb]"+v"(pb2), [t]"=&v"(tmp), [cnt]"=&s"(scnt)
                        : [ptr]"v"(ap), [tag]"s"(tag)
                        : "vcc", "scc", "memory");
                    if ((pa & 0xffffu) == tag) break;
                } while (--budget > 0);
                // drain any remaining in-flight poll before consuming pa
                asm volatile("s_waitcnt vmcnt(0)" ::: "memory");
                hprev[u] = __uint_as_float(pa & 0xffff0000u);
            }
            __syncthreads();   // barrier A: full h_{s-1} in hprev
            asm volatile("" :: "v"(pa), "v"(pb2));
        }

        // matvec: 192 rows; 16-lane k-split, 96 FMAs/lane, 4-stage xor-reduce.
        float a0 = 0.f, a1 = 0.f, a2 = 0.f;
        #pragma unroll
        for (int m = 0; m < 8; ++m) {
            float4 h4 = hp4[m * 16 + l4];
            a0 = fmaf(wf0[m].x, h4.x, a0); a0 = fmaf(wf0[m].y, h4.y, a0);
            a0 = fmaf(wf0[m].z, h4.z, a0); a0 = fmaf(wf0[m].w, h4.w, a0);
            a1 = fmaf(wf1[m].x, h4.x, a1); a1 = fmaf(wf1[m].y, h4.y, a1);
            a1 = fmaf(wf1[m].z, h4.z, a1); a1 = fmaf(wf1[m].w, h4.w, a1);
            a2 = fmaf(wf2[m].x, h4.x, a2); a2 = fmaf(wf2[m].y, h4.y, a2);
            a2 = fmaf(wf2[m].z, h4.z, a2); a2 = fmaf(wf2[m].w, h4.w, a2);
        }
        #pragma unroll
        for (int o = 1; o < 16; o <<= 1) {
            a0 += __shfl_xor(a0, o, 64);
            a1 += __shfl_xor(a1, o, 64);
            a2 += __shfl_xor(a2, o, 64);
        }
        if (l4 == 0) {
            gsum[rr0]     = a0 + bl0;
            gsum[rr0 + 1] = a1 + bl1;
            gsum[rr0 + 2] = a2 + bl2;
        }
        __syncthreads();       // barrier B: gsum complete; all hprev reads done

        if (tid < HU) {        // gate wave: full 64 lanes, one unit each
            float gr  = gir + gsum[tid];
            float gz  = giz + gsum[HU + tid];
            float ghn = gsum[2 * HU + tid];
            float r = __builtin_amdgcn_rcpf(1.f + __expf(-gr));
            float z = __builtin_amdgcn_rcpf(1.f + __expf(-gz));
            float xt = gin + r * ghn;
            float n = 1.f - 2.f * __builtin_amdgcn_rcpf(__expf(2.f * xt) + 1.f);
            float hn = (1.f - z) * n + z * hreg;
            hreg = hn;
            // publish FIRST: {bf16 h | 16-bit tag}, 64 lanes coalesced (1 line)
            unsigned ub = __float_as_uint(hn);
            ub += 0x7fffu + ((ub >> 16) & 1u);        // RNE f32 -> bf16
            unsigned pay = (ub & 0xffff0000u) | ((unsigned)(s + 1) & 0xffffu);
            __hip_atomic_store(&hcomm[(size_t)s * NPAY + jbase + tid], pay,
                               __ATOMIC_RELAXED, __HIP_MEMORY_SCOPE_AGENT);
            int j = jbase + tid;
            hs[(size_t)s * DOUTD + j] = hn;   // normal store; attn is a later kernel
            hprev[j] = hn;                    // self-publish own chunk
            if (s + 1 < TT) {  // ready-gated gi prefetch (shadowed by remote polls)
                while (__hip_atomic_load(&ready[s + 1], __ATOMIC_RELAXED,
                                         __HIP_MEMORY_SCOPE_AGENT) == 0u) {
                    if (--rbudget < 0) break;
                }
                const float* gn = gi + (size_t)(s + 1) * G3;
                gir = __hip_atomic_load(&gn[j], __ATOMIC_RELAXED, __HIP_MEMORY_SCOPE_AGENT);
                giz = __hip_atomic_load(&gn[DOUTD + j], __ATOMIC_RELAXED, __HIP_MEMORY_SCOPE_AGENT);
                gin = __hip_atomic_load(&gn[2 * DOUTD + j], __ATOMIC_RELAXED, __HIP_MEMORY_SCOPE_AGENT);
            }
        }
    }
}

// ---------------- attention epilogue ----------------
__global__ void attn_kernel(const float* __restrict__ hs, const float* __restrict__ q,
                            const float* __restrict__ log_lam, float* __restrict__ out) {
    int tid = threadIdx.x;   // 512
    int wave = tid >> 6, lane = tid & 63;
    __shared__ float sc[TT];
    __shared__ float at[TT];
    __shared__ float red[8];
    __shared__ float red2[8];
    __shared__ float denom_s, mx_s;

    const float qscale = 0.04419417382415921757f;  // 1/sqrt(512)
    for (int r = wave; r < TT; r += 8) {
        float acc = 0.f;
        #pragma unroll
        for (int m = 0; m < 8; ++m) {
            int k = lane + 64 * m;
            acc = fmaf(hs[(size_t)r * DOUTD + k], q[k], acc);
        }
        for (int o = 32; o; o >>= 1) acc += __shfl_down(acc, o, 64);
        if (lane == 0) sc[r] = acc * qscale;
    }
    __syncthreads();
    float lam = fmaxf(expf(log_lam[0]), 1e-4f);
    float s_i = sc[tid] - lam * (float)(TT - 1 - tid);

    float mval = s_i;
    for (int o = 32; o; o >>= 1) mval = fmaxf(mval, __shfl_down(mval, o, 64));
    if (lane == 0) red[wave] = mval;
    __syncthreads();
    if (tid == 0) {
        float mm = red[0];
        for (int i = 1; i < 8; ++i) mm = fmaxf(mm, red[i]);
        mx_s = mm;
    }
    __syncthreads();
    float e = expf(s_i - mx_s);
    float ssum = e;
    for (int o = 32; o; o >>= 1) ssum += __shfl_down(ssum, o, 64);
    if (lane == 0) red2[wave] = ssum;
    __syncthreads();
    if (tid == 0) {
        float dsum = 0.f;
        for (int i = 0; i < 8; ++i) dsum += red2[i];
        denom_s = dsum;
    }
    __syncthreads();
    float attn = e / denom_s;
    out[DOUTD + tid] = attn;     // output 1: attn (T,)
    at[tid] = attn;
    __syncthreads();
    float acc = 0.f;
    for (int i = 0; i < TT; ++i) acc = fmaf(at[i], hs[(size_t)i * DOUTD + tid], acc);
    out[tid] = acc;              // output 0: summary (1, 512)
}

extern "C" void kernel_launch(void* const* d_in, const int* in_sizes, int n_in,
                              void* d_out, int out_size, void* d_ws, size_t ws_size,
                              hipStream_t stream) {
    const int*   idx    = (const int*)d_in[0];
    const float* timef  = (const float*)d_in[1];
    const float* emb    = (const float*)d_in[2];
    const float* latlon = (const float*)d_in[3];
    const float* lnw    = (const float*)d_in[4];
    const float* lnb    = (const float*)d_in[5];
    const float* w1     = (const float*)d_in[6];
    const float* b1     = (const float*)d_in[7];
    const float* w2     = (const float*)d_in[8];
    const float* b2     = (const float*)d_in[9];
    const float* wih    = (const float*)d_in[10];  // (1536, 256)
    const float* whh    = (const float*)d_in[11];  // (1536, 512)
    const float* bih    = (const float*)d_in[12];  // (1536,)
    const float* bhh    = (const float*)d_in[13];  // (1536,)
    const float* q      = (const float*)d_in[14];
    const float* loglam = (const float*)d_in[15];
    float* out = (float*)d_out;

    unsigned* hcomm = (unsigned*)d_ws;                       // 512*512 dwords (1 MB)
    unsigned* ready = hcomm + (size_t)TT * NPAY;             // 512 dwords
    float* gi = (float*)(ready + TT);                        // 512*1536 = 786432
    float* hs = gi + (size_t)TT * G3;                        // 512*512 = 262144

    init_kernel<<<256, 256, 0, stream>>>((uint4*)d_ws);
    mega_kernel<<<GB + PREB, 1024, 0, stream>>>(idx, timef, latlon, emb, lnw, lnb,
                                                w1, b1, w2, b2, wih, bih, whh, bhh,
                                                gi, hs, hcomm, ready);
    attn_kernel<<<1, TT, 0, stream>>>(hs, q, loglam, out);
}

// Round 8
// 1540.502 us; speedup vs baseline: 1.3609x; 1.3609x over previous
//
#include <hip/hip_runtime.h>
#include <math.h>

#define TT 512
#define DPOI 256
#define DIN 260
#define DHID 356
#define DOUTD 512
#define G3 1536

// GRU partition: 16 worker blocks x 1024 threads, 32 hidden units per block.
// R5-proven protocol: agent-scope 4B {bf16 h | 16-bit tag} payloads, 2-deep
// phase-staggered pipelined polling (race-fixed), normal L2-cached gi
// prefetch (pre_kernel runs in a prior dispatch). GB=16 halves the per-CU
// matvec serialization vs GB=8 (96 rows/CU instead of 192). Attention is
// fused into the same kernel: workers agent-store hs, drain once (vmcnt 0),
// set done[b]; block 0 polls the 16 done flags then runs attn with NORMAL
// loads (hs lines cannot be stale: L2 invalidated at dispatch start, hs only
// agent-stored since).
#define GB 16
#define HU (DOUTD / GB)      // 32 hidden units per block
#define NRR (3 * HU)         // 96 w_hh rows per block
#define NPAY DOUTD           // 512 dword payload units per step

// ---------------- fused pre-kernel: features + LN + MLP1 + MLP2 + gi ----------------
// One block per timestep t; xn/h1/x2 live only in LDS. Also zeroes this
// block's hcomm slice + (block 0) the done flags; dispatch-end writeback
// makes the zeros visible to the GRU kernel's agent-scope reads.
__global__ __launch_bounds__(512)
void pre_kernel(const int* __restrict__ idx, const float* __restrict__ timef,
                const float* __restrict__ latlon, const float* __restrict__ emb,
                const float* __restrict__ lnw, const float* __restrict__ lnb,
                const float* __restrict__ w1, const float* __restrict__ b1,
                const float* __restrict__ w2, const float* __restrict__ b2,
                const float* __restrict__ wih, const float* __restrict__ bih,
                float* __restrict__ gi, unsigned* __restrict__ hcz,
                unsigned* __restrict__ done) {
    int t = blockIdx.x;
    int tid = threadIdx.x;           // 512 threads
    int wave = tid >> 6, lane = tid & 63;

    __shared__ float xl[DIN];
    __shared__ float h1l[DHID];
    __shared__ alignas(16) float x2l[DPOI];
    __shared__ float red[8];
    __shared__ float mu_s, rs_s;

    // zero this block's slice of hcomm step-tags (+ done flags from block 0)
    hcz[(size_t)t * 512 + tid] = 0u;
    if (t == 0 && tid < 64) done[tid] = 0u;

    // --- features (redundant per thread; only tid<4 consume) ---
    float tv = fminf(fmaxf(timef[t], 0.f), 1.f);
    const float TWO_PI = 6.28318530717958647692f;
    float f0 = sinf(TWO_PI * tv);
    float f1 = cosf(TWO_PI * tv);
    float f2 = 0.f, f3 = 0.f;
    if (t > 0) {
        float tp = fminf(fmaxf(timef[t - 1], 0.f), 1.f);
        float d = tv - tp;
        d = d - floorf(d);          // jnp.mod(x, 1.0)
        f2 = log1pf(d * 24.f);
        int i0 = idx[t - 1], i1 = idx[t];
        float la0 = latlon[2 * (size_t)i0], lo0 = latlon[2 * (size_t)i0 + 1];
        float la1 = latlon[2 * (size_t)i1], lo1 = latlon[2 * (size_t)i1 + 1];
        const float D2R = 0.01745329251994329577f;
        float lat1 = fminf(fmaxf(la0, -90.f), 90.f) * D2R;
        float lon1 = fminf(fmaxf(lo0, -180.f), 180.f) * D2R;
        float lat2 = fminf(fmaxf(la1, -90.f), 90.f) * D2R;
        float lon2 = fminf(fmaxf(lo1, -180.f), 180.f) * D2R;
        float dlat = (lat2 - lat1) * 0.5f, dlon = (lon2 - lon1) * 0.5f;
        float sdlat = sinf(dlat), sdlon = sinf(dlon);
        float a = sdlat * sdlat +
                  fminf(fmaxf(cosf(lat1), -1.f), 1.f) * fminf(fmaxf(cosf(lat2), -1.f), 1.f) * sdlon * sdlon;
        float aa = fminf(fmaxf(a, 0.f), 1.f);
        float bb = fminf(fmaxf(1.f - a, 1e-12f), 1.f);
        float cc = 2.f * atan2f(sqrtf(aa), sqrtf(bb));
        f3 = log1pf(6371.0088f * cc);
    }
    float fv = (tid == 0) ? f0 : (tid == 1) ? f1 : (tid == 2) ? f2 : f3;

    float v0 = (tid < 256) ? emb[(size_t)idx[t] * DPOI + tid] : 0.f;
    float v1 = (tid < 4) ? fv : 0.f;

    // --- layernorm over 260 elements (8-wave reduce; waves 4-7 contribute 0) ---
    float s = v0 + v1;
    for (int o = 32; o; o >>= 1) s += __shfl_down(s, o, 64);
    if (lane == 0) red[wave] = s;
    __syncthreads();
    if (tid == 0) {
        float mm = 0.f;
        for (int i = 0; i < 8; ++i) mm += red[i];
        mu_s = mm * (1.f / 260.f);
    }
    __syncthreads();
    float mu = mu_s;
    float d0 = (tid < 256) ? (v0 - mu) : 0.f;
    float d1 = (tid < 4) ? (v1 - mu) : 0.f;
    float sq = d0 * d0 + d1 * d1;
    for (int o = 32; o; o >>= 1) sq += __shfl_down(sq, o, 64);
    __syncthreads();
    if (lane == 0) red[wave] = sq;
    __syncthreads();
    if (tid == 0) {
        float vv = 0.f;
        for (int i = 0; i < 8; ++i) vv += red[i];
        rs_s = rsqrtf(vv * (1.f / 260.f) + 1e-5f);
    }
    __syncthreads();
    float rs = rs_s;
    if (tid < 256) xl[tid] = d0 * rs * lnw[tid] + lnb[tid];
    if (tid < 4)   xl[256 + tid] = d1 * rs * lnw[256 + tid] + lnb[256 + tid];
    __syncthreads();

    // --- mlp1: x @ w1 + b1, gelu -> h1 (LDS) ---
    if (tid < DHID) {
        float acc = b1[tid];
        #pragma unroll 4
        for (int k = 0; k < DIN; ++k) acc = fmaf(xl[k], w1[k * DHID + tid], acc);
        h1l[tid] = 0.5f * acc * (1.f + erff(acc * 0.70710678118654752440f));
    }
    __syncthreads();

    // --- mlp2: h1 @ w2 + b2 -> x2 (LDS) ---
    if (tid < DPOI) {
        float acc = b2[tid];
        #pragma unroll 4
        for (int k = 0; k < DHID; ++k) acc = fmaf(h1l[k], w2[k * DPOI + tid], acc);
        x2l[tid] = acc;
    }
    __syncthreads();

    // --- gi: x2 @ w_ih.T + b_ih (1536 rows over 8 waves) ---
    float4 xv = ((const float4*)x2l)[lane];
    for (int r = wave; r < G3; r += 8) {
        float4 wv = ((const float4*)(wih + (size_t)r * DPOI))[lane];
        float sd = xv.x * wv.x + xv.y * wv.y + xv.z * wv.z + xv.w * wv.w;
        for (int o = 32; o; o >>= 1) sd += __shfl_down(sd, o, 64);
        if (lane == 0) gi[(size_t)t * G3 + r] = sd + bih[r];
    }
}

// ---------------- GRU scan (GB=16) + fused attention epilogue ----------------
__global__ __launch_bounds__(1024)
void gru_attn_kernel(const float* __restrict__ gi, const float* __restrict__ whh,
                     const float* __restrict__ bhh, float* __restrict__ hs,
                     unsigned* __restrict__ hcomm, unsigned* __restrict__ done,
                     const float* __restrict__ q, const float* __restrict__ log_lam,
                     float* __restrict__ out) {
    __shared__ alignas(16) float hprev[DOUTD];   // 2 KB
    __shared__ float gsum[NRR];                  // 384 B
    __shared__ float sc[TT];                     // attn scratch (block 0 only)
    __shared__ float at[TT];
    __shared__ float red[8];
    __shared__ float red2[8];
    __shared__ float denom_s, mx_s;

    int b = blockIdx.x;        // 0..15
    int tid = threadIdx.x;     // 0..1023
    int wave = tid >> 6, lane = tid & 63;
    int jbase = b * HU;
    int g2 = lane >> 5, l5 = lane & 31;
    int rr0 = wave * 6 + g2 * 3;       // this 32-lane group's 3 rows (of 96)

    // --- W_hh fragments -> f32 registers. Lane covers k = m*128 + l5*4 + {0..3},
    //     m = 0..3 (48 VGPR of W per lane). Row rr -> whh[(rr>>5)*512 + jbase + (rr&31)].
    float4 wf0[4], wf1[4], wf2[4];
    float bl0, bl1, bl2;
    {
        int r0 = rr0, r1 = rr0 + 1, r2 = rr0 + 2;
        const float4* p0 = (const float4*)(whh + (size_t)((r0 >> 5) * DOUTD + jbase + (r0 & 31)) * DOUTD);
        const float4* p1 = (const float4*)(whh + (size_t)((r1 >> 5) * DOUTD + jbase + (r1 & 31)) * DOUTD);
        const float4* p2 = (const float4*)(whh + (size_t)((r2 >> 5) * DOUTD + jbase + (r2 & 31)) * DOUTD);
        #pragma unroll
        for (int m = 0; m < 4; ++m) {
            wf0[m] = p0[m * 32 + l5];
            wf1[m] = p1[m * 32 + l5];
            wf2[m] = p2[m * 32 + l5];
        }
        bl0 = bhh[(r0 >> 5) * DOUTD + jbase + (r0 & 31)];
        bl1 = bhh[(r1 >> 5) * DOUTD + jbase + (r1 & 31)];
        bl2 = bhh[(r2 >> 5) * DOUTD + jbase + (r2 & 31)];
    }
    if (tid < DOUTD) hprev[tid] = 0.f;
    __syncthreads();

    const float4* hp4 = (const float4*)hprev;
    long budget = 3000;        // poll-loop re-entry budget (deadlock -> numeric fail)

    // gi prefetch (gate lanes), one step ahead; NORMAL cached loads (pre ran in
    // a prior dispatch; L2 serves these off the critical path). Own h in reg.
    float gir = 0.f, giz = 0.f, gin = 0.f, hreg = 0.f;
    if (tid < HU) {
        int j = jbase + tid;
        gir = gi[j];
        giz = gi[DOUTD + j];
        gin = gi[2 * DOUTD + j];
    }

    for (int s = 0; s < TT; ++s) {
        unsigned pa = 0, pb2 = 0;
        if (s > 0) {
            // waves 4..11 poll unit u = (wave-4)*64 + lane (512 units); the 32
            // lanes covering our own block's units skip (self-published).
            bool poller = (wave >= 4 && wave < 12);
            int u = ((wave - 4) << 6) + lane;
            if (poller && (u >> 5) != b) {
                const unsigned* ap = hcomm + (size_t)(s - 1) * NPAY + u;
                unsigned tag = (unsigned)s & 0xffffu;   // producer stored ((s-1)+1)
                // prime slot A
                asm volatile("global_load_dword %0, %1, off sc0 sc1"
                             : "=v"(pa) : "v"(ap) : "memory");
                // stagger ~RT/2: dependent FMA chain
                float xx = (float)(lane + 1) * 1e-6f;
                #pragma unroll
                for (int qq = 0; qq < 256; ++qq) xx = fmaf(xx, 1.0000002f, 1.1920929e-7f);
                // prime slot B (chain feeds in as dummy input -> ordered after spin)
                asm volatile("global_load_dword %0, %1, off sc0 sc1"
                             : "=v"(pb2) : "v"(ap), "v"(xx) : "memory");
                // 2-deep round-robin pipelined poll; tag-gated; bounded.
                do {
                    unsigned tmp; int scnt;
                    asm volatile(
                        "s_movk_i32 %[cnt], 64\n\t"
                        "1:\n\t"
                        "s_waitcnt vmcnt(1)\n\t"
                        "v_and_b32 %[t], 0xffff, %[pa]\n\t"
                        "v_cmp_ne_u32 vcc, %[tag], %[t]\n\t"
                        "s_cbranch_vccz 9f\n\t"
                        "global_load_dword %[pa], %[ptr], off sc0 sc1\n\t"
                        "s_waitcnt vmcnt(1)\n\t"
                        "v_and_b32 %[t], 0xffff, %[pb]\n\t"
                        "v_cmp_ne_u32 vcc, %[tag], %[t]\n\t"
                        "s_cbranch_vccz 8f\n\t"
                        "global_load_dword %[pb], %[ptr], off sc0 sc1\n\t"
                        "s_sub_u32 %[cnt], %[cnt], 1\n\t"
                        "s_cmp_lg_u32 %[cnt], 0\n\t"
                        "s_cbranch_scc1 1b\n\t"
                        "s_branch 9f\n\t"
                        "8:\n\t"
                        "s_waitcnt vmcnt(0)\n\t"          // drain pa's in-flight reload
                        "v_mov_b32 %[pa], %[pb]\n\t"
                        "9:\n\t"
                        : [pa]"+v"(pa), [pb]"+v"(pb2), [t]"=&v"(tmp), [cnt]"=&s"(scnt)
                        : [ptr]"v"(ap), [tag]"s"(tag)
                        : "vcc", "scc", "memory");
                    if ((pa & 0xffffu) == tag) break;
                } while (--budget > 0);
                // drain any remaining in-flight poll before consuming pa
                asm volatile("s_waitcnt vmcnt(0)" ::: "memory");
                hprev[u] = __uint_as_float(pa & 0xffff0000u);
            }
            __syncthreads();   // barrier A: full h_{s-1} in hprev
            asm volatile("" :: "v"(pa), "v"(pb2));
        }

        // matvec: 96 rows; 32-lane k-split, 48 FMAs/lane, 5-stage xor-reduce.
        float a0 = 0.f, a1 = 0.f, a2 = 0.f;
        #pragma unroll
        for (int m = 0; m < 4; ++m) {
            float4 h4 = hp4[m * 32 + l5];
            a0 = fmaf(wf0[m].x, h4.x, a0); a0 = fmaf(wf0[m].y, h4.y, a0);
            a0 = fmaf(wf0[m].z, h4.z, a0); a0 = fmaf(wf0[m].w, h4.w, a0);
            a1 = fmaf(wf1[m].x, h4.x, a1); a1 = fmaf(wf1[m].y, h4.y, a1);
            a1 = fmaf(wf1[m].z, h4.z, a1); a1 = fmaf(wf1[m].w, h4.w, a1);
            a2 = fmaf(wf2[m].x, h4.x, a2); a2 = fmaf(wf2[m].y, h4.y, a2);
            a2 = fmaf(wf2[m].z, h4.z, a2); a2 = fmaf(wf2[m].w, h4.w, a2);
        }
        #pragma unroll
        for (int o = 1; o < 32; o <<= 1) {   // xor stays within the 32-lane group
            a0 += __shfl_xor(a0, o, 64);
            a1 += __shfl_xor(a1, o, 64);
            a2 += __shfl_xor(a2, o, 64);
        }
        if (l5 == 0) {
            gsum[rr0]     = a0 + bl0;
            gsum[rr0 + 1] = a1 + bl1;
            gsum[rr0 + 2] = a2 + bl2;
        }
        __syncthreads();       // barrier B: gsum complete; all hprev reads done

        if (tid < HU) {        // gate lanes 0..31 of wave 0
            float gr  = gir + gsum[tid];
            float gz  = giz + gsum[HU + tid];
            float ghn = gsum[2 * HU + tid];
            float r = __builtin_amdgcn_rcpf(1.f + __expf(-gr));
            float z = __builtin_amdgcn_rcpf(1.f + __expf(-gz));
            float xt = gin + r * ghn;
            float n = 1.f - 2.f * __builtin_amdgcn_rcpf(__expf(2.f * xt) + 1.f);
            float hn = (1.f - z) * n + z * hreg;
            hreg = hn;
            // publish FIRST: {bf16 h | 16-bit tag}, 32 lanes = one 128B line
            unsigned ub = __float_as_uint(hn);
            ub += 0x7fffu + ((ub >> 16) & 1u);        // RNE f32 -> bf16
            unsigned pay = (ub & 0xffff0000u) | ((unsigned)(s + 1) & 0xffffu);
            __hip_atomic_store(&hcomm[(size_t)s * NPAY + jbase + tid], pay,
                               __ATOMIC_RELAXED, __HIP_MEMORY_SCOPE_AGENT);
            int j = jbase + tid;
            // agent-scope write-through: lands at the coherence point so block
            // 0's post-done normal loads (L2-miss -> MALL) see it.
            __hip_atomic_store(&hs[(size_t)s * DOUTD + j], hn,
                               __ATOMIC_RELAXED, __HIP_MEMORY_SCOPE_AGENT);
            hprev[j] = hn;                    // self-publish own chunk
            if (s + 1 < TT) {                 // prefetch next step's gi (cached)
                const float* gn = gi + (size_t)(s + 1) * G3;
                gir = gn[j]; giz = gn[DOUTD + j]; gin = gn[2 * DOUTD + j];
            }
        }
    }

    // --- drain all stores to the coherence point, then signal completion ---
    asm volatile("s_waitcnt vmcnt(0)" ::: "memory");
    __syncthreads();
    if (tid == 0)
        __hip_atomic_store(&done[b], 1u, __ATOMIC_RELAXED, __HIP_MEMORY_SCOPE_AGENT);
    if (b != 0) return;

    // ---------------- fused attention epilogue (block 0) ----------------
    {
        long dbud = 20L * 1000 * 1000;
        if (tid < GB) {
            while (__hip_atomic_load(&done[tid], __ATOMIC_RELAXED,
                                     __HIP_MEMORY_SCOPE_AGENT) == 0u) {
                if (--dbud < 0) break;
            }
        }
        __syncthreads();   // all hs at MALL; normal loads below are safe (no
                           // stale L2 lines: invalidated at dispatch start,
                           // hs only agent-stored since)
    }

    const float qscale = 0.04419417382415921757f;  // 1/sqrt(512)
    for (int r = wave; r < TT; r += 16) {
        float acc = 0.f;
        #pragma unroll
        for (int m = 0; m < 8; ++m) {
            int k = lane + 64 * m;
            acc = fmaf(hs[(size_t)r * DOUTD + k], q[k], acc);
        }
        for (int o = 32; o; o >>= 1) acc += __shfl_down(acc, o, 64);
        if (lane == 0) sc[r] = acc * qscale;
    }
    __syncthreads();
    float lam = fmaxf(expf(log_lam[0]), 1e-4f);
    float s_i = (tid < TT) ? (sc[tid] - lam * (float)(TT - 1 - tid)) : -1e30f;

    float mval = s_i;
    for (int o = 32; o; o >>= 1) mval = fmaxf(mval, __shfl_down(mval, o, 64));
    if (lane == 0 && wave < 8) red[wave] = mval;
    __syncthreads();
    if (tid == 0) {
        float mm = red[0];
        for (int i = 1; i < 8; ++i) mm = fmaxf(mm, red[i]);
        mx_s = mm;
    }
    __syncthreads();
    float e = (tid < TT) ? expf(s_i - mx_s) : 0.f;
    float ssum = e;
    for (int o = 32; o; o >>= 1) ssum += __shfl_down(ssum, o, 64);
    if (lane == 0 && wave < 8) red2[wave] = ssum;
    __syncthreads();
    if (tid == 0) {
        float dsum = 0.f;
        for (int i = 0; i < 8; ++i) dsum += red2[i];
        denom_s = dsum;
    }
    __syncthreads();
    if (tid < TT) {
        float attn = e / denom_s;
        out[DOUTD + tid] = attn;     // output 1: attn (T,)
        at[tid] = attn;
    }
    __syncthreads();
    if (tid < TT) {
        float acc = 0.f;
        for (int i = 0; i < TT; ++i) acc = fmaf(at[i], hs[(size_t)i * DOUTD + tid], acc);
        out[tid] = acc;              // output 0: summary (1, 512)
    }
}

extern "C" void kernel_launch(void* const* d_in, const int* in_sizes, int n_in,
                              void* d_out, int out_size, void* d_ws, size_t ws_size,
                              hipStream_t stream) {
    const int*   idx    = (const int*)d_in[0];
    const float* timef  = (const float*)d_in[1];
    const float* emb    = (const float*)d_in[2];
    const float* latlon = (const float*)d_in[3];
    const float* lnw    = (const float*)d_in[4];
    const float* lnb    = (const float*)d_in[5];
    const float* w1     = (const float*)d_in[6];
    const float* b1     = (const float*)d_in[7];
    const float* w2     = (const float*)d_in[8];
    const float* b2     = (const float*)d_in[9];
    const float* wih    = (const float*)d_in[10];  // (1536, 256)
    const float* whh    = (const float*)d_in[11];  // (1536, 512)
    const float* bih    = (const float*)d_in[12];  // (1536,)
    const float* bhh    = (const float*)d_in[13];  // (1536,)
    const float* q      = (const float*)d_in[14];
    const float* loglam = (const float*)d_in[15];
    float* out = (float*)d_out;

    unsigned* hcomm = (unsigned*)d_ws;                       // 512*512 dwords (1 MB)
    unsigned* done  = hcomm + (size_t)TT * NPAY;             // 64 dwords
    float* gi = (float*)(done + 64);                         // 512*1536 = 786432
    float* hs = gi + (size_t)TT * G3;                        // 512*512 = 262144

    pre_kernel<<<TT, 512, 0, stream>>>(idx, timef, latlon, emb, lnw, lnb,
                                       w1, b1, w2, b2, wih, bih, gi, hcomm, done);
    gru_attn_kernel<<<GB, 1024, 0, stream>>>(gi, whh, bhh, hs, hcomm, done,
                                             q, loglam, out);
}